// Round 5
// baseline (216.659 us; speedup 1.0000x reference)
//
#include <hip/hip_runtime.h>
#include <hip/hip_bf16.h>
#include <math.h>

// Problem constants
// B=32, C=64 (Cin==Cout), N=8192, modes F=32, L=20 segments, M=8 Chebyshev
#define NN    8192
#define NROWS 2048      // B*C
#define FF    32
#define LM    160       // L*M

// Workspace layout (float offsets)
// TRIG4 layout: [k4][f][4] : ws[TRIG + (k4*64+f)*4 + j] =
//   f<32 ? cos(2pi f (4k4+j)/N) : sin(2pi (f-32)(4k4+j)/N)
// TRIGT layout: [f][n] row-major (rows 0..31 cos, 32..63 sin) — for k_inv streaming
static constexpr int TRIG   = 0;         // 2048*64*4 = 524288 floats
static constexpr int W1RT   = 524288;    // [f][i][o] 32*64*64
static constexpr int W1IT   = 655360;
static constexpr int GWT    = 786432;    // [i][o] 64*64
static constexpr int AR_    = 790528;    // [160][32]
static constexpr int AI_    = 795648;
static constexpr int WL_    = 800768;    // [160]
static constexpr int WR_    = 800928;
static constexpr int IL_    = 801088;    // int [160]
static constexpr int IR_    = 801248;
static constexpr int XR_    = 801408;    // [2048][32]
static constexpr int XI_    = 866944;
static constexpr int GN_    = 932480;    // [2048][32]
static constexpr int ARAI   = 998016;    // [2048][64]: [0..31]=cos coeff, [32..63]=sin coeff
static constexpr int TRIGT_ = 1129088;   // [64][8192] = 524288 floats
// total = 1653376 floats = 6.31 MB

#define PI_D 3.14159265358979323846

// ---------------- A1: trig tables (both layouts) ----------------
__global__ __launch_bounds__(256) void k_trig(float* __restrict__ ws) {
  int idx = blockIdx.x * 256 + threadIdx.x;   // 0..524287
  int k4 = idx >> 8, f = (idx >> 2) & 63, j = idx & 3;
  int n = 4 * k4 + j;
  int fr = f & 31;
  int p = (fr * n) & (NN - 1);
  float ang = (float)p * (float)(2.0 * PI_D / (double)NN);
  float s, c;
  sincosf(ang, &s, &c);
  float v = (f < 32) ? c : s;
  ws[TRIG + idx] = v;
  ws[TRIGT_ + f * NN + n] = v;
}

// ---------------- A2: CFT constant tables (double precision, parallel) ----------------
__global__ __launch_bounds__(256) void k_cft_tables(float* __restrict__ ws) {
  int tid = blockIdx.x * 256 + threadIdx.x;
  if (tid >= LM * FF) return;
  int j = tid >> 5, f = tid & 31;
  int l = j >> 3, m = j & 7;      // m doubles as Chebyshev order k
  double cheb[8];
  #pragma unroll
  for (int mm = 0; mm < 8; ++mm)
    cheb[mm] = -cos((2.0 * mm + 1.0) * PI_D / 16.0);

  double Wr = 0.0, Wi = 0.0;
  #pragma unroll
  for (int mm = 0; mm < 8; ++mm) {
    double T = cos((double)m * acos(cheb[mm]));
    double ang = cheb[mm] * (double)f * (PI_D * 0.05);
    Wr += T * cos(ang);
    Wi += T * (-sin(ang));
  }
  Wr *= 0.025; Wi *= 0.025;
  double phi = 2.0 * PI_D * ((double)l * 0.05) * (double)f;
  double cs = cos(phi), sn = sin(phi);
  ws[AR_ + j * FF + f] = (float)(Wr * cs + Wi * sn);
  ws[AI_ + j * FF + f] = (float)(-Wr * sn + Wi * cs);

  if (f == 0) {
    double v = (double)l * 0.05 + 0.025 * (cheb[m] + 1.0);
    int r = (int)(v * 8191.0);
    while ((double)r / 8191.0 < v) ++r;
    while (r > 0 && (double)(r - 1) / 8191.0 >= v) --r;
    if (r > 8191) r = 8191;
    int le = r - 1; if (le < 0) le = 0;
    double tl = (double)le / 8191.0, tr = (double)r / 8191.0;
    double den = (tr - tl == 0.0) ? 1.0 : (tr - tl);
    double wr = (v - tl) / den;
    ws[WL_ + j] = (float)(1.0 - wr);
    ws[WR_ + j] = (float)wr;
    ((int*)ws)[IL_ + j] = le;
    ((int*)ws)[IR_ + j] = r;
  }
}

// ---------------- A3: transposes ----------------
__global__ __launch_bounds__(256) void k_transpose(const float* __restrict__ w1r,
                                                   const float* __restrict__ w1i,
                                                   const float* __restrict__ gw,
                                                   float* __restrict__ ws) {
  int idx = blockIdx.x * 256 + threadIdx.x;   // 0..131071
  if (idx >= 32 * 64 * 64) return;
  int o = idx & 63, i = (idx >> 6) & 63, f = idx >> 12;   // f in 0..31
  ws[W1RT + (f * 64 + i) * 64 + o] = w1r[(i * 64 + o) * FF + f];
  ws[W1IT + (f * 64 + i) * 64 + o] = w1i[(i * 64 + o) * FF + f];
  if (idx < 4096) {
    ws[GWT + idx] = gw[(idx & 63) * 64 + (idx >> 6)];
  }
}

// ---------------- B1: forward truncated DFT, split-K GEMM w/ LDS-staged x ----------------
// grid = 32 row-tiles x 64 K-chunks (chunk = 128 k, single LDS stage, 32 KB).
// Block 256 thr = 4 waves; wave w: rows rt*64+w*16..+15, lane = f (0-31 cos, 32-63 sin).
// x from LDS same-address broadcast ds_read_b128; trig via coalesced float4 w/ prefetch.
// Partials -> part[kc][row][64] in d_out (64*2048*64 floats = 33.5 MB).
__global__ __launch_bounds__(256) void k_fwd_gemm(const float* __restrict__ x,
                                                  const float* __restrict__ ws,
                                                  float* __restrict__ part) {
  __shared__ __align__(16) float xs[64 * 128];   // 32 KB
  const int rt = blockIdx.x >> 6, kc = blockIdx.x & 63;
  const int t = threadIdx.x;
  const int w = t >> 6, lane = t & 63;
  const int rblock = rt * 64;
  const float4* __restrict__ tg4 = (const float4*)(ws + TRIG);
  const int k40 = kc * 32;                       // 32 k4-iters = 128 k per chunk

  // issue first trig load before staging so latency hides behind the barrier
  float4 tg = tg4[(size_t)k40 * 64 + lane];

  const int c4 = t & 31, r0 = t >> 5;            // staging: 32 float4/row, 8 rows/pass
  const int kb = kc * 128;
  #pragma unroll
  for (int p = 0; p < 8; ++p) {
    int row = r0 + 8 * p;
    float4 v = *(const float4*)(x + (size_t)(rblock + row) * NN + kb + c4 * 4);
    *(float4*)(&xs[row * 128 + c4 * 4]) = v;
  }

  float acc[16];
  #pragma unroll
  for (int r = 0; r < 16; ++r) acc[r] = 0.f;

  __syncthreads();

#define FWD_STEP(IT, TGV)                                                       \
  {                                                                             \
    const float* xw = &xs[(w * 16) * 128 + (IT) * 4];                           \
    _Pragma("unroll")                                                           \
    for (int r = 0; r < 16; ++r) {                                              \
      float4 xv = *(const float4*)(xw + r * 128);                               \
      acc[r] = fmaf(xv.w, (TGV).w, fmaf(xv.z, (TGV).z,                          \
               fmaf(xv.y, (TGV).y, fmaf(xv.x, (TGV).x, acc[r]))));              \
    }                                                                           \
  }

  #pragma unroll 4
  for (int it = 0; it < 31; ++it) {
    float4 tgn = tg4[(size_t)(k40 + it + 1) * 64 + lane];   // prefetch next
    FWD_STEP(it, tg);
    tg = tgn;
  }
  FWD_STEP(31, tg);
#undef FWD_STEP

  float* __restrict__ pp = part + ((size_t)kc * NROWS + rblock + w * 16) * 64 + lane;
  #pragma unroll
  for (int r = 0; r < 16; ++r)
    pp[(size_t)r * 64] = acc[r];
}

// ---------------- B2: split-K reduce -> XR_/XI_ ----------------
__global__ __launch_bounds__(256) void k_fred(const float* __restrict__ part,
                                              float* __restrict__ ws) {
  int idx = blockIdx.x * 256 + threadIdx.x;   // 0..131071
  int row = idx >> 6, f = idx & 63;
  float s = 0.f;
  #pragma unroll 8
  for (int kc = 0; kc < 64; ++kc)
    s += part[((size_t)kc * NROWS + row) * 64 + f];
  if (f < 32) ws[XR_ + row * FF + f] = s;
  else        ws[XI_ + row * FF + (f - 32)] = -s;   // rfft imag = -sum x sin
}

// ---------------- B3: CFT magnitude + LayerNorm (per row) ----------------
__global__ __launch_bounds__(256) void k_cft(const float* __restrict__ x,
                                             const float* __restrict__ gamma,
                                             const float* __restrict__ beta,
                                             float* __restrict__ ws) {
  const int sub = threadIdx.x >> 6, li = threadIdx.x & 63;
  const int row = blockIdx.x * 4 + sub;
  const float* __restrict__ xr = x + (size_t)row * NN;
  __shared__ float seg[4][LM];
  #pragma unroll
  for (int g = 0; g < 3; ++g) {
    int j = li + 64 * g;
    if (j < LM) {
      int il = ((const int*)ws)[IL_ + j];
      int ir = ((const int*)ws)[IR_ + j];
      seg[sub][j] = ws[WL_ + j] * xr[il] + ws[WR_ + j] * xr[ir];
    }
  }
  __syncthreads();
  if (li < FF) {
    float re = 0.f, im = 0.f;
    #pragma unroll 8
    for (int j = 0; j < LM; ++j) {
      float sv = seg[sub][j];
      re = fmaf(sv, ws[AR_ + j * FF + li], re);
      im = fmaf(sv, ws[AI_ + j * FF + li], im);
    }
    float mag = sqrtf(re * re + im * im);
    float mu = mag;
    mu += __shfl_xor(mu, 1);  mu += __shfl_xor(mu, 2);  mu += __shfl_xor(mu, 4);
    mu += __shfl_xor(mu, 8);  mu += __shfl_xor(mu, 16);
    mu *= (1.0f / 32.0f);
    float d = mag - mu;
    float vv = d * d;
    vv += __shfl_xor(vv, 1);  vv += __shfl_xor(vv, 2);  vv += __shfl_xor(vv, 4);
    vv += __shfl_xor(vv, 8);  vv += __shfl_xor(vv, 16);
    vv *= (1.0f / 32.0f);
    float g = d / sqrtf(vv + 1e-5f) * gamma[li] + beta[li];
    ws[GN_ + row * FF + li] = g;
  }
}

// ---------------- C: gate (LN -> 1x1 conv -> sigmoid) + complex channel mix ----------------
__global__ __launch_bounds__(64) void k_gate(float* __restrict__ ws) {
  int bidx = blockIdx.x;                 // b*32 + f
  int b = bidx >> 5, f = bidx & 31;
  int o = threadIdx.x;
  __shared__ float gn[64], gr[64], gi[64];
  int rowb = b * 64;
  gn[o] = ws[GN_ + (rowb + o) * FF + f];
  float xre = ws[XR_ + (rowb + o) * FF + f];
  float xim = ws[XI_ + (rowb + o) * FF + f];
  __syncthreads();
  float acc = 0.f;
  #pragma unroll 16
  for (int i = 0; i < 64; ++i)
    acc = fmaf(ws[GWT + i * 64 + o], gn[i], acc);
  float gate = 1.0f / (1.0f + expf(-acc));
  gr[o] = xre * gate;
  gi[o] = xim * gate;
  __syncthreads();
  float Yr = 0.f, Yi = 0.f;
  const float* __restrict__ w1rt = ws + W1RT + f * 4096;
  const float* __restrict__ w1it = ws + W1IT + f * 4096;
  #pragma unroll 8
  for (int i = 0; i < 64; ++i) {
    float a = gr[i], bb2 = gi[i];
    float wr = w1rt[i * 64 + o], wi = w1it[i * 64 + o];
    Yr = fmaf(a, wr, Yr); Yr = fmaf(-bb2, wi, Yr);
    Yi = fmaf(a, wi, Yi); Yi = fmaf(bb2, wr, Yi);
  }
  float* A = ws + ARAI + (size_t)(rowb + o) * 64;
  if (f == 0) {
    A[0]  = Yr * (1.0f / (float)NN);
    A[32] = 0.0f;
  } else {
    A[f]      = Yr * (2.0f / (float)NN);
    A[32 + f] = -Yi * (2.0f / (float)NN);
  }
}

// ---------------- D: inverse (2048x64)@(64x8192) GEMM, trig streamed from L2 ----------------
// grid = 64 row-tiles(32 rows) x 32 col-tiles(256 cols) = 2048 blocks.
// LDS = A-tile 32x64 (8 KB, broadcast operand); TRIGT[f][n] streamed coalesced + prefetch.
// Wave w: rows bb*32 + w*8 .. +7; lane covers 4 cols (lane*4).
__global__ __launch_bounds__(256) void k_inv(const float* __restrict__ ws,
                                             float* __restrict__ out) {
  __shared__ __align__(16) float As[32 * 64];     // 8 KB
  const int blk = blockIdx.x;
  const int bb = blk >> 5, cc = blk & 31;
  const int t = threadIdx.x;
  const int w = t >> 6, lane = t & 63;
  const int rowbase = bb * 32;
  const float* __restrict__ trigt = ws + TRIGT_;
  const int colb = cc * 256 + lane * 4;

  // prefetch first trig group before staging A
  float4 tg0 = *(const float4*)(trigt + (size_t)0 * NN + colb);
  float4 tg1 = *(const float4*)(trigt + (size_t)1 * NN + colb);
  float4 tg2 = *(const float4*)(trigt + (size_t)2 * NN + colb);
  float4 tg3 = *(const float4*)(trigt + (size_t)3 * NN + colb);

  #pragma unroll
  for (int p = 0; p < 2; ++p) {
    int idx = t + 256 * p;                        // 0..511 -> 512 float4 = 2048 floats
    int r = idx >> 4, q = idx & 15;
    *(float4*)(&As[r * 64 + q * 4]) =
        *(const float4*)(ws + ARAI + (size_t)(rowbase + r) * 64 + q * 4);
  }

  float4 acc[8];
  #pragma unroll
  for (int r = 0; r < 8; ++r) acc[r] = make_float4(0.f, 0.f, 0.f, 0.f);

  __syncthreads();

#define INV_STEP(F0)                                                            \
  {                                                                             \
    _Pragma("unroll")                                                           \
    for (int r = 0; r < 8; ++r) {                                               \
      float4 av = *(const float4*)(&As[(w * 8 + r) * 64 + (F0)]);               \
      acc[r].x = fmaf(av.x, tg0.x, acc[r].x); acc[r].y = fmaf(av.x, tg0.y, acc[r].y); \
      acc[r].z = fmaf(av.x, tg0.z, acc[r].z); acc[r].w = fmaf(av.x, tg0.w, acc[r].w); \
      acc[r].x = fmaf(av.y, tg1.x, acc[r].x); acc[r].y = fmaf(av.y, tg1.y, acc[r].y); \
      acc[r].z = fmaf(av.y, tg1.z, acc[r].z); acc[r].w = fmaf(av.y, tg1.w, acc[r].w); \
      acc[r].x = fmaf(av.z, tg2.x, acc[r].x); acc[r].y = fmaf(av.z, tg2.y, acc[r].y); \
      acc[r].z = fmaf(av.z, tg2.z, acc[r].z); acc[r].w = fmaf(av.z, tg2.w, acc[r].w); \
      acc[r].x = fmaf(av.w, tg3.x, acc[r].x); acc[r].y = fmaf(av.w, tg3.y, acc[r].y); \
      acc[r].z = fmaf(av.w, tg3.z, acc[r].z); acc[r].w = fmaf(av.w, tg3.w, acc[r].w); \
    }                                                                           \
  }

  for (int fo = 0; fo < 15; ++fo) {
    int f0 = fo * 4;
    float4 n0 = *(const float4*)(trigt + (size_t)(f0 + 4) * NN + colb);
    float4 n1 = *(const float4*)(trigt + (size_t)(f0 + 5) * NN + colb);
    float4 n2 = *(const float4*)(trigt + (size_t)(f0 + 6) * NN + colb);
    float4 n3 = *(const float4*)(trigt + (size_t)(f0 + 7) * NN + colb);
    INV_STEP(f0);
    tg0 = n0; tg1 = n1; tg2 = n2; tg3 = n3;
  }
  INV_STEP(60);
#undef INV_STEP

  #pragma unroll
  for (int r = 0; r < 8; ++r) {
    int row = rowbase + w * 8 + r;
    *(float4*)(out + (size_t)row * NN + colb) = acc[r];
  }
}

extern "C" void kernel_launch(void* const* d_in, const int* in_sizes, int n_in,
                              void* d_out, int out_size, void* d_ws, size_t ws_size,
                              hipStream_t stream) {
  const float* x     = (const float*)d_in[0];   // (32,64,8192)
  const float* w1r   = (const float*)d_in[1];   // (64,64,32)
  const float* w1i   = (const float*)d_in[2];   // (64,64,32)
  const float* gw    = (const float*)d_in[3];   // (64,64)
  const float* gamma = (const float*)d_in[4];   // (32,)
  const float* beta  = (const float*)d_in[5];   // (32,)
  float* out = (float*)d_out;                   // (32,64,8192)
  float* ws = (float*)d_ws;
  // split-K partials live in d_out (33.5 MB of its 64 MB) — fully overwritten by k_inv later
  float* part = (float*)d_out;

  hipLaunchKernelGGL(k_trig,       dim3(2048), dim3(256), 0, stream, ws);
  hipLaunchKernelGGL(k_cft_tables, dim3(20),   dim3(256), 0, stream, ws);
  hipLaunchKernelGGL(k_transpose,  dim3(512),  dim3(256), 0, stream, w1r, w1i, gw, ws);
  hipLaunchKernelGGL(k_fwd_gemm,   dim3(2048), dim3(256), 0, stream, x, ws, part);
  hipLaunchKernelGGL(k_fred,       dim3(512),  dim3(256), 0, stream, part, ws);
  hipLaunchKernelGGL(k_cft,        dim3(512),  dim3(256), 0, stream, x, gamma, beta, ws);
  hipLaunchKernelGGL(k_gate,       dim3(1024), dim3(64),  0, stream, ws);
  hipLaunchKernelGGL(k_inv,        dim3(2048), dim3(256), 0, stream, ws, out);
}

// Round 6
// 212.417 us; speedup vs baseline: 1.0200x; 1.0200x over previous
//
#include <hip/hip_runtime.h>
#include <hip/hip_bf16.h>
#include <math.h>

// Problem constants
// B=32, C=64 (Cin==Cout), N=8192, modes F=32, L=20 segments, M=8 Chebyshev
#define NN    8192
#define NROWS 2048      // B*C
#define FF    32
#define LM    160       // L*M

// Workspace layout (float offsets)
// TRIG4 layout: [k4][f][4] : ws[TRIG + (k4*64+f)*4 + j] =
//   f<32 ? cos(2pi f (4k4+j)/N) : sin(2pi (f-32)(4k4+j)/N)
// TRIGT layout: [f][n] row-major (rows 0..31 cos, 32..63 sin) — for k_inv streaming
static constexpr int TRIG   = 0;         // 2048*64*4 = 524288 floats
static constexpr int W1RT   = 524288;    // [f][i][o] 32*64*64
static constexpr int W1IT   = 655360;
static constexpr int GWT    = 786432;    // [i][o] 64*64
static constexpr int AR_    = 790528;    // [160][32]
static constexpr int AI_    = 795648;
static constexpr int WL_    = 800768;    // [160]
static constexpr int WR_    = 800928;
static constexpr int IL_    = 801088;    // int [160]
static constexpr int IR_    = 801248;
static constexpr int XR_    = 801408;    // [2048][32]
static constexpr int XI_    = 866944;
static constexpr int GN_    = 932480;    // [2048][32]
static constexpr int ARAI   = 998016;    // [2048][64]: [0..31]=cos coeff, [32..63]=sin coeff
static constexpr int TRIGT_ = 1129088;   // [64][8192] = 524288 floats
// total = 1653376 floats = 6.31 MB

#define PI_D 3.14159265358979323846

// ---------------- A1: trig tables (both layouts) ----------------
__global__ __launch_bounds__(256) void k_trig(float* __restrict__ ws) {
  int idx = blockIdx.x * 256 + threadIdx.x;   // 0..524287
  int k4 = idx >> 8, f = (idx >> 2) & 63, j = idx & 3;
  int n = 4 * k4 + j;
  int fr = f & 31;
  int p = (fr * n) & (NN - 1);
  float ang = (float)p * (float)(2.0 * PI_D / (double)NN);
  float s, c;
  sincosf(ang, &s, &c);
  float v = (f < 32) ? c : s;
  ws[TRIG + idx] = v;
  ws[TRIGT_ + f * NN + n] = v;
}

// ---------------- A2: CFT constant tables (double precision, parallel) ----------------
__global__ __launch_bounds__(256) void k_cft_tables(float* __restrict__ ws) {
  int tid = blockIdx.x * 256 + threadIdx.x;
  if (tid >= LM * FF) return;
  int j = tid >> 5, f = tid & 31;
  int l = j >> 3, m = j & 7;      // m doubles as Chebyshev order k
  double cheb[8];
  #pragma unroll
  for (int mm = 0; mm < 8; ++mm)
    cheb[mm] = -cos((2.0 * mm + 1.0) * PI_D / 16.0);

  double Wr = 0.0, Wi = 0.0;
  #pragma unroll
  for (int mm = 0; mm < 8; ++mm) {
    double T = cos((double)m * acos(cheb[mm]));
    double ang = cheb[mm] * (double)f * (PI_D * 0.05);
    Wr += T * cos(ang);
    Wi += T * (-sin(ang));
  }
  Wr *= 0.025; Wi *= 0.025;
  double phi = 2.0 * PI_D * ((double)l * 0.05) * (double)f;
  double cs = cos(phi), sn = sin(phi);
  ws[AR_ + j * FF + f] = (float)(Wr * cs + Wi * sn);
  ws[AI_ + j * FF + f] = (float)(-Wr * sn + Wi * cs);

  if (f == 0) {
    double v = (double)l * 0.05 + 0.025 * (cheb[m] + 1.0);
    int r = (int)(v * 8191.0);
    while ((double)r / 8191.0 < v) ++r;
    while (r > 0 && (double)(r - 1) / 8191.0 >= v) --r;
    if (r > 8191) r = 8191;
    int le = r - 1; if (le < 0) le = 0;
    double tl = (double)le / 8191.0, tr = (double)r / 8191.0;
    double den = (tr - tl == 0.0) ? 1.0 : (tr - tl);
    double wr = (v - tl) / den;
    ws[WL_ + j] = (float)(1.0 - wr);
    ws[WR_ + j] = (float)wr;
    ((int*)ws)[IL_ + j] = le;
    ((int*)ws)[IR_ + j] = r;
  }
}

// ---------------- A3: transposes ----------------
__global__ __launch_bounds__(256) void k_transpose(const float* __restrict__ w1r,
                                                   const float* __restrict__ w1i,
                                                   const float* __restrict__ gw,
                                                   float* __restrict__ ws) {
  int idx = blockIdx.x * 256 + threadIdx.x;   // 0..131071
  if (idx >= 32 * 64 * 64) return;
  int o = idx & 63, i = (idx >> 6) & 63, f = idx >> 12;   // f in 0..31
  ws[W1RT + (f * 64 + i) * 64 + o] = w1r[(i * 64 + o) * FF + f];
  ws[W1IT + (f * 64 + i) * 64 + o] = w1i[(i * 64 + o) * FF + f];
  if (idx < 4096) {
    ws[GWT + idx] = gw[(idx & 63) * 64 + (idx >> 6)];
  }
}

// ---------------- B1: forward truncated DFT, split-K GEMM, half-wave 2x reuse ----------------
// grid = 32 row-tiles x 64 K-chunks (chunk = 128 k, 32 KB LDS).
// Block 256 = 4 waves. Each lane: f = lane&31, accumulates BOTH cos and sin sums
// for 8 rows; lane<32 -> rows w*16..+7, lane>=32 -> rows w*16+8..+15.
// ds_read_b128 has 2 distinct addrs/wave (2-way broadcast = free, m136); per k4-iter:
// 8 ds + 2 global(L2) trig + 64 fma  -> 1:8 LDS:FMA (half of R5's traffic).
__global__ __launch_bounds__(256) void k_fwd_gemm(const float* __restrict__ x,
                                                  const float* __restrict__ ws,
                                                  float* __restrict__ part) {
  __shared__ __align__(16) float xs[64 * 128];   // 32 KB
  const int rt = blockIdx.x >> 6, kc = blockIdx.x & 63;
  const int t = threadIdx.x;
  const int w = t >> 6, lane = t & 63;
  const int half = lane >> 5, fl = lane & 31;
  const int rblock = rt * 64;
  const float4* __restrict__ tg4 = (const float4*)(ws + TRIG);
  const int k40 = kc * 32;                       // 32 k4-iters = 128 k per chunk

  // first trig loads (cos + sin rows for f=fl) before staging
  float4 tc = tg4[(size_t)k40 * 64 + fl];
  float4 tn = tg4[(size_t)k40 * 64 + 32 + fl];

  const int c4 = t & 31, r0 = t >> 5;            // staging: 32 float4/row, 8 rows/pass
  const int kb = kc * 128;
  #pragma unroll
  for (int p = 0; p < 8; ++p) {
    int row = r0 + 8 * p;
    float4 v = *(const float4*)(x + (size_t)(rblock + row) * NN + kb + c4 * 4);
    *(float4*)(&xs[row * 128 + c4 * 4]) = v;
  }

  float accC[8], accS[8];
  #pragma unroll
  for (int r = 0; r < 8; ++r) { accC[r] = 0.f; accS[r] = 0.f; }

  __syncthreads();

  const float* __restrict__ xbase = &xs[(w * 16 + half * 8) * 128];

#define FWD_STEP(IT, TC, TS)                                                    \
  {                                                                             \
    _Pragma("unroll")                                                           \
    for (int j = 0; j < 8; ++j) {                                               \
      float4 xv = *(const float4*)(xbase + j * 128 + (IT) * 4);                 \
      accC[j] = fmaf(xv.w, (TC).w, fmaf(xv.z, (TC).z,                           \
                fmaf(xv.y, (TC).y, fmaf(xv.x, (TC).x, accC[j]))));              \
      accS[j] = fmaf(xv.w, (TS).w, fmaf(xv.z, (TS).z,                           \
                fmaf(xv.y, (TS).y, fmaf(xv.x, (TS).x, accS[j]))));              \
    }                                                                           \
  }

  #pragma unroll 4
  for (int it = 0; it < 31; ++it) {
    float4 tc2 = tg4[(size_t)(k40 + it + 1) * 64 + fl];        // prefetch next
    float4 tn2 = tg4[(size_t)(k40 + it + 1) * 64 + 32 + fl];
    FWD_STEP(it, tc, tn);
    tc = tc2; tn = tn2;
  }
  FWD_STEP(31, tc, tn);
#undef FWD_STEP

  // rows: rblock + w*16 + half*8 + j ; cols: fl (cos) and fl+32 (sin, k_fred negates)
  float* __restrict__ pp = part + ((size_t)kc * NROWS + rblock + w * 16 + half * 8) * 64;
  #pragma unroll
  for (int j = 0; j < 8; ++j) {
    pp[j * 64 + fl]      = accC[j];
    pp[j * 64 + 32 + fl] = accS[j];
  }
}

// ---------------- B2: split-K reduce -> XR_/XI_ ----------------
__global__ __launch_bounds__(256) void k_fred(const float* __restrict__ part,
                                              float* __restrict__ ws) {
  int idx = blockIdx.x * 256 + threadIdx.x;   // 0..131071
  int row = idx >> 6, f = idx & 63;
  float s = 0.f;
  #pragma unroll 8
  for (int kc = 0; kc < 64; ++kc)
    s += part[((size_t)kc * NROWS + row) * 64 + f];
  if (f < 32) ws[XR_ + row * FF + f] = s;
  else        ws[XI_ + row * FF + (f - 32)] = -s;   // rfft imag = -sum x sin
}

// ---------------- B3: CFT magnitude + LayerNorm (per row) ----------------
__global__ __launch_bounds__(256) void k_cft(const float* __restrict__ x,
                                             const float* __restrict__ gamma,
                                             const float* __restrict__ beta,
                                             float* __restrict__ ws) {
  const int sub = threadIdx.x >> 6, li = threadIdx.x & 63;
  const int row = blockIdx.x * 4 + sub;
  const float* __restrict__ xr = x + (size_t)row * NN;
  __shared__ float seg[4][LM];
  #pragma unroll
  for (int g = 0; g < 3; ++g) {
    int j = li + 64 * g;
    if (j < LM) {
      int il = ((const int*)ws)[IL_ + j];
      int ir = ((const int*)ws)[IR_ + j];
      seg[sub][j] = ws[WL_ + j] * xr[il] + ws[WR_ + j] * xr[ir];
    }
  }
  __syncthreads();
  if (li < FF) {
    float re = 0.f, im = 0.f;
    #pragma unroll 8
    for (int j = 0; j < LM; ++j) {
      float sv = seg[sub][j];
      re = fmaf(sv, ws[AR_ + j * FF + li], re);
      im = fmaf(sv, ws[AI_ + j * FF + li], im);
    }
    float mag = sqrtf(re * re + im * im);
    float mu = mag;
    mu += __shfl_xor(mu, 1);  mu += __shfl_xor(mu, 2);  mu += __shfl_xor(mu, 4);
    mu += __shfl_xor(mu, 8);  mu += __shfl_xor(mu, 16);
    mu *= (1.0f / 32.0f);
    float d = mag - mu;
    float vv = d * d;
    vv += __shfl_xor(vv, 1);  vv += __shfl_xor(vv, 2);  vv += __shfl_xor(vv, 4);
    vv += __shfl_xor(vv, 8);  vv += __shfl_xor(vv, 16);
    vv *= (1.0f / 32.0f);
    float g = d / sqrtf(vv + 1e-5f) * gamma[li] + beta[li];
    ws[GN_ + row * FF + li] = g;
  }
}

// ---------------- C: gate (LN -> 1x1 conv -> sigmoid) + complex channel mix ----------------
__global__ __launch_bounds__(64) void k_gate(float* __restrict__ ws) {
  int bidx = blockIdx.x;                 // b*32 + f
  int b = bidx >> 5, f = bidx & 31;
  int o = threadIdx.x;
  __shared__ float gn[64], gr[64], gi[64];
  int rowb = b * 64;
  gn[o] = ws[GN_ + (rowb + o) * FF + f];
  float xre = ws[XR_ + (rowb + o) * FF + f];
  float xim = ws[XI_ + (rowb + o) * FF + f];
  __syncthreads();
  float acc = 0.f;
  #pragma unroll 16
  for (int i = 0; i < 64; ++i)
    acc = fmaf(ws[GWT + i * 64 + o], gn[i], acc);
  float gate = 1.0f / (1.0f + expf(-acc));
  gr[o] = xre * gate;
  gi[o] = xim * gate;
  __syncthreads();
  float Yr = 0.f, Yi = 0.f;
  const float* __restrict__ w1rt = ws + W1RT + f * 4096;
  const float* __restrict__ w1it = ws + W1IT + f * 4096;
  #pragma unroll 8
  for (int i = 0; i < 64; ++i) {
    float a = gr[i], bb2 = gi[i];
    float wr = w1rt[i * 64 + o], wi = w1it[i * 64 + o];
    Yr = fmaf(a, wr, Yr); Yr = fmaf(-bb2, wi, Yr);
    Yi = fmaf(a, wi, Yi); Yi = fmaf(bb2, wr, Yi);
  }
  float* A = ws + ARAI + (size_t)(rowb + o) * 64;
  if (f == 0) {
    A[0]  = Yr * (1.0f / (float)NN);
    A[32] = 0.0f;
  } else {
    A[f]      = Yr * (2.0f / (float)NN);
    A[32 + f] = -Yi * (2.0f / (float)NN);
  }
}

// ---------------- D: inverse (2048x64)@(64x8192) GEMM, trig streamed from L2 ----------------
__global__ __launch_bounds__(256) void k_inv(const float* __restrict__ ws,
                                             float* __restrict__ out) {
  __shared__ __align__(16) float As[32 * 64];     // 8 KB
  const int blk = blockIdx.x;
  const int bb = blk >> 5, cc = blk & 31;
  const int t = threadIdx.x;
  const int w = t >> 6, lane = t & 63;
  const int rowbase = bb * 32;
  const float* __restrict__ trigt = ws + TRIGT_;
  const int colb = cc * 256 + lane * 4;

  float4 tg0 = *(const float4*)(trigt + (size_t)0 * NN + colb);
  float4 tg1 = *(const float4*)(trigt + (size_t)1 * NN + colb);
  float4 tg2 = *(const float4*)(trigt + (size_t)2 * NN + colb);
  float4 tg3 = *(const float4*)(trigt + (size_t)3 * NN + colb);

  #pragma unroll
  for (int p = 0; p < 2; ++p) {
    int idx = t + 256 * p;
    int r = idx >> 4, q = idx & 15;
    *(float4*)(&As[r * 64 + q * 4]) =
        *(const float4*)(ws + ARAI + (size_t)(rowbase + r) * 64 + q * 4);
  }

  float4 acc[8];
  #pragma unroll
  for (int r = 0; r < 8; ++r) acc[r] = make_float4(0.f, 0.f, 0.f, 0.f);

  __syncthreads();

#define INV_STEP(F0)                                                            \
  {                                                                             \
    _Pragma("unroll")                                                           \
    for (int r = 0; r < 8; ++r) {                                               \
      float4 av = *(const float4*)(&As[(w * 8 + r) * 64 + (F0)]);               \
      acc[r].x = fmaf(av.x, tg0.x, acc[r].x); acc[r].y = fmaf(av.x, tg0.y, acc[r].y); \
      acc[r].z = fmaf(av.x, tg0.z, acc[r].z); acc[r].w = fmaf(av.x, tg0.w, acc[r].w); \
      acc[r].x = fmaf(av.y, tg1.x, acc[r].x); acc[r].y = fmaf(av.y, tg1.y, acc[r].y); \
      acc[r].z = fmaf(av.y, tg1.z, acc[r].z); acc[r].w = fmaf(av.y, tg1.w, acc[r].w); \
      acc[r].x = fmaf(av.z, tg2.x, acc[r].x); acc[r].y = fmaf(av.z, tg2.y, acc[r].y); \
      acc[r].z = fmaf(av.z, tg2.z, acc[r].z); acc[r].w = fmaf(av.z, tg2.w, acc[r].w); \
      acc[r].x = fmaf(av.w, tg3.x, acc[r].x); acc[r].y = fmaf(av.w, tg3.y, acc[r].y); \
      acc[r].z = fmaf(av.w, tg3.z, acc[r].z); acc[r].w = fmaf(av.w, tg3.w, acc[r].w); \
    }                                                                           \
  }

  for (int fo = 0; fo < 15; ++fo) {
    int f0 = fo * 4;
    float4 n0 = *(const float4*)(trigt + (size_t)(f0 + 4) * NN + colb);
    float4 n1 = *(const float4*)(trigt + (size_t)(f0 + 5) * NN + colb);
    float4 n2 = *(const float4*)(trigt + (size_t)(f0 + 6) * NN + colb);
    float4 n3 = *(const float4*)(trigt + (size_t)(f0 + 7) * NN + colb);
    INV_STEP(f0);
    tg0 = n0; tg1 = n1; tg2 = n2; tg3 = n3;
  }
  INV_STEP(60);
#undef INV_STEP

  #pragma unroll
  for (int r = 0; r < 8; ++r) {
    int row = rowbase + w * 8 + r;
    *(float4*)(out + (size_t)row * NN + colb) = acc[r];
  }
}

extern "C" void kernel_launch(void* const* d_in, const int* in_sizes, int n_in,
                              void* d_out, int out_size, void* d_ws, size_t ws_size,
                              hipStream_t stream) {
  const float* x     = (const float*)d_in[0];   // (32,64,8192)
  const float* w1r   = (const float*)d_in[1];   // (64,64,32)
  const float* w1i   = (const float*)d_in[2];   // (64,64,32)
  const float* gw    = (const float*)d_in[3];   // (64,64)
  const float* gamma = (const float*)d_in[4];   // (32,)
  const float* beta  = (const float*)d_in[5];   // (32,)
  float* out = (float*)d_out;                   // (32,64,8192)
  float* ws = (float*)d_ws;
  // split-K partials live in d_out (33.5 MB of its 64 MB) — fully overwritten by k_inv later
  float* part = (float*)d_out;

  hipLaunchKernelGGL(k_trig,       dim3(2048), dim3(256), 0, stream, ws);
  hipLaunchKernelGGL(k_cft_tables, dim3(20),   dim3(256), 0, stream, ws);
  hipLaunchKernelGGL(k_transpose,  dim3(512),  dim3(256), 0, stream, w1r, w1i, gw, ws);
  hipLaunchKernelGGL(k_fwd_gemm,   dim3(2048), dim3(256), 0, stream, x, ws, part);
  hipLaunchKernelGGL(k_fred,       dim3(512),  dim3(256), 0, stream, part, ws);
  hipLaunchKernelGGL(k_cft,        dim3(512),  dim3(256), 0, stream, x, gamma, beta, ws);
  hipLaunchKernelGGL(k_gate,       dim3(1024), dim3(64),  0, stream, ws);
  hipLaunchKernelGGL(k_inv,        dim3(2048), dim3(256), 0, stream, ws, out);
}